// Round 13
// baseline (12923.085 us; speedup 1.0000x reference)
//
#include <hip/hip_runtime.h>
#include <math.h>

// Elman RNN, R13: R11 base + x@W1x hoisted out of the recurrence (Phase A GEMM).
// batch=64,T=2048,in=256,hid=512,out=256 fp32.
// Phase A: xw[b,t,c] = sum_k x[b,t,k]*W1[512+k][c]  (tiled 64x64x64 GEMM, 16384 blocks).
// Phase B: 256 blocks = 4 groups(16 rows) x 64 col-groups(8 h-cols,4 y-cols).
//   R11-proven protocol: targeted per-thread poll (producer blk tid>>2, rotating
//   per-step flags) -> stage h u64 -> fused h/y-GEMM (K=512) from LDS + regs ->
//   swizzled-scratch reduce -> reducer adds xwv (loaded at iter top; done before
//   publish vmcnt per R9 rule) -> tanh -> agent store -> block vmcnt -> flag.
// Evidence base: FETCH 1.6GB/dispatch in R5..R11 = x duplication (4MB/step)
// thrashing IF$ -> h-line HBM misses -> straggler tail. xw slice/blk = 512B/step.
// Fallback: if ws_size < 272MB, launch verbatim R11 kernel (passed, 11.7ms).
// Numerics: recurrence fp32 (error amp ~1e4, R1); h exchange bit-exact.

#define BB 64
#define TT 2048
#define II 256
#define HH 512
#define OO 256
#define NBLK 256
#define OUT_OFF ((size_t)BB * TT * OO)
#define FLAGS_INTS ((TT + 1) * NBLK)
#define XW_OFF (4ull * 1024 * 1024)
#define XW_BYTES ((size_t)BB * TT * HH * 4)

typedef unsigned long long ull;
typedef float fx4 __attribute__((ext_vector_type(4)));

__global__ void rnn_init(int* __restrict__ flags) {
    int i = blockIdx.x * blockDim.x + threadIdx.x;
    if (i < FLAGS_INTS) flags[i] = 0;
}

// ---------------- Phase A: xw = x @ W1_x (M=131072, N=512, K=256) ------------
__global__ __launch_bounds__(256) void xw_gemm(
    const float* __restrict__ x, const float* __restrict__ W1,
    float* __restrict__ xw)
{
    __shared__ float As[64][68];   // [k][m] transposed
    __shared__ float Bs[64][68];   // [k][n]
    const int tid = threadIdx.x;
    const int m0 = (int)(blockIdx.x >> 3) << 6;
    const int n0 = (int)(blockIdx.x & 7) << 6;
    const int tx = tid & 15, ty = tid >> 4;

    float acc[4][4];
    #pragma unroll
    for (int r = 0; r < 4; ++r)
        #pragma unroll
        for (int c = 0; c < 4; ++c) acc[r][c] = 0.f;

    for (int kp = 0; kp < II; kp += 64) {
        #pragma unroll
        for (int u = 0; u < 4; ++u) {
            int e = (u << 8) + tid;            // 0..1023 float4 units
            int row = e >> 4;                  // 0..63
            int k4  = (e & 15) << 2;           // 0..60
            float4 v = *(const float4*)&x[(size_t)(m0 + row) * II + kp + k4];
            As[k4 + 0][row] = v.x; As[k4 + 1][row] = v.y;
            As[k4 + 2][row] = v.z; As[k4 + 3][row] = v.w;
            *(float4*)&Bs[row][k4] = *(const float4*)&W1[(size_t)(HH + kp + row) * HH + n0 + k4];
        }
        __syncthreads();
        #pragma unroll 8
        for (int kk = 0; kk < 64; ++kk) {
            float4 av = *(const float4*)&As[kk][ty << 2];
            float4 bv = *(const float4*)&Bs[kk][tx << 2];
            float aa[4] = { av.x, av.y, av.z, av.w };
            float bb[4] = { bv.x, bv.y, bv.z, bv.w };
            #pragma unroll
            for (int r = 0; r < 4; ++r)
                #pragma unroll
                for (int c = 0; c < 4; ++c)
                    acc[r][c] = fmaf(aa[r], bb[c], acc[r][c]);
        }
        __syncthreads();
    }
    #pragma unroll
    for (int r = 0; r < 4; ++r) {
        float4 v = make_float4(acc[r][0], acc[r][1], acc[r][2], acc[r][3]);
        *(float4*)&xw[(size_t)(m0 + (ty << 2) + r) * HH + n0 + (tx << 2)] = v;
    }
}

// ---------------- Phase B: recurrence (R11 minus x, plus xwv) ----------------
__global__ __launch_bounds__(256, 1) void rnn_persist_xw(
    const float* __restrict__ xwp, const float* __restrict__ W1,
    const float* __restrict__ b1, const float* __restrict__ W2,
    const float* __restrict__ b2, float* __restrict__ out,
    int* __restrict__ flags, float* __restrict__ hbuf)
{
    __shared__ float v_s[16 * HH];
    __shared__ float sc_h[128 * 64];
    __shared__ float sc_y[64 * 64];

    const int tid = threadIdx.x;
    const int blk = blockIdx.x;
    const int bi  = blk >> 6;
    const int cj  = blk & 63;
    const int R0  = bi << 4;
    const int C0  = cj << 3;
    const int O0  = cj << 2;

    const int g  = tid & 63;
    const int rq = tid >> 6;

    float w1r[2][4][8];
    #pragma unroll
    for (int jj = 0; jj < 2; ++jj)
        #pragma unroll
        for (int i = 0; i < 4; ++i) {
            const float* wp = W1 + (size_t)((jj << 8) + (g << 2) + i) * HH + C0;
            float4 a = *(const float4*)wp;
            float4 b = *(const float4*)(wp + 4);
            w1r[jj][i][0]=a.x; w1r[jj][i][1]=a.y; w1r[jj][i][2]=a.z; w1r[jj][i][3]=a.w;
            w1r[jj][i][4]=b.x; w1r[jj][i][5]=b.y; w1r[jj][i][6]=b.z; w1r[jj][i][7]=b.w;
        }
    float w2r[2][4][4];
    #pragma unroll
    for (int jj = 0; jj < 2; ++jj)
        #pragma unroll
        for (int i = 0; i < 4; ++i) {
            float4 a = *(const float4*)(W2 + (size_t)((jj << 8) + (g << 2) + i) * OO + O0);
            w2r[jj][i][0]=a.x; w2r[jj][i][1]=a.y; w2r[jj][i][2]=a.z; w2r[jj][i][3]=a.w;
        }
    const float b1v = (tid < 128) ? b1[C0 + (tid & 7)] : 0.f;
    const float b2v = (tid >= 128 && tid < 192) ? b2[O0 + ((tid - 128) & 3)] : 0.f;

    float* hb[2] = { hbuf, hbuf + (size_t)BB * HH };

    #pragma unroll
    for (int m = 0; m < 8; ++m)
        *(float4*)&v_s[((m << 8) + tid) << 2] = make_float4(0.f, 0.f, 0.f, 0.f);
    __syncthreads();

    for (int t = 0; t < TT; ++t) {
        // xw slice for this step (latency hides under poll+stage+GEMM)
        float xwv = 0.f;
        if (tid < 128)
            xwv = xwp[((size_t)(R0 + (tid >> 3)) * TT + t) * HH + C0 + (tid & 7)];

        if (t > 0) {
            const int* fp = flags + (size_t)t * NBLK + (bi << 6) + (tid >> 2);
            while (__hip_atomic_load((int*)fp, __ATOMIC_RELAXED,
                                     __HIP_MEMORY_SCOPE_AGENT) == 0) {}
            const ull* hsrc = (const ull*)hb[t & 1];
            ull* vd = (ull*)v_s;
            #pragma unroll
            for (int half = 0; half < 2; ++half) {
                ull hl[8];
                #pragma unroll
                for (int m = 0; m < 8; ++m) {
                    int row = (half << 3) + m;
                    hl[m] = __hip_atomic_load(
                        (ull*)&hsrc[(size_t)(R0 + row) * (HH / 2) + tid],
                        __ATOMIC_RELAXED, __HIP_MEMORY_SCOPE_AGENT);
                }
                #pragma unroll
                for (int m = 0; m < 8; ++m) {
                    int row = (half << 3) + m;
                    vd[row * (HH / 2) + tid] = hl[m];
                }
            }
        }
        __syncthreads();                  // S1

        float pa[4][8];
        float py[4][4];
        #pragma unroll
        for (int r = 0; r < 4; ++r) {
            #pragma unroll
            for (int c = 0; c < 8; ++c) pa[r][c] = 0.f;
            #pragma unroll
            for (int o = 0; o < 4; ++o) py[r][o] = 0.f;
        }
        #pragma unroll
        for (int r = 0; r < 4; ++r) {
            const float* vrow = v_s + (rq + (r << 2)) * HH;
            #pragma unroll
            for (int jj = 0; jj < 2; ++jj) {
                float4 vv = *(const float4*)(vrow + (jj << 8) + (g << 2));
                float vva[4] = { vv.x, vv.y, vv.z, vv.w };
                #pragma unroll
                for (int i = 0; i < 4; ++i) {
                    const float vi = vva[i];
                    #pragma unroll
                    for (int c = 0; c < 8; ++c)
                        pa[r][c] = fmaf(vi, w1r[jj][i][c], pa[r][c]);
                    #pragma unroll
                    for (int o = 0; o < 4; ++o)
                        py[r][o] = fmaf(vi, w2r[jj][i][o], py[r][o]);
                }
            }
        }
        #pragma unroll
        for (int r = 0; r < 4; ++r) {
            const int row = rq + (r << 2);
            #pragma unroll
            for (int c = 0; c < 8; ++c) {
                const int u = (row << 3) + c;
                sc_h[(u << 6) + (g ^ ((u & 15) << 2))] = pa[r][c];
            }
            #pragma unroll
            for (int o = 0; o < 4; ++o) {
                const int u = (row << 2) + o;
                sc_y[(u << 6) + (g ^ ((u & 15) << 2))] = py[r][o];
            }
        }
        __syncthreads();                  // S2

        if (tid < 128) {
            float s = 0.f;
            #pragma unroll
            for (int j = 0; j < 16; ++j) {
                float4 q = *(const float4*)&sc_h[(tid << 6) + ((j << 2) ^ ((tid & 15) << 2))];
                s += (q.x + q.y) + (q.z + q.w);
            }
            float hv = tanhf(s + xwv + b1v);
            __hip_atomic_store(&hb[(t + 1) & 1][(size_t)(R0 + (tid >> 3)) * HH + C0 + (tid & 7)],
                               hv, __ATOMIC_RELAXED, __HIP_MEMORY_SCOPE_AGENT);
            if (t == TT - 1)
                out[OUT_OFF + (size_t)(R0 + (tid >> 3)) * HH + C0 + (tid & 7)] = hv;
        } else if (tid < 192 && t > 0) {
            const int u = tid - 128;
            float s = 0.f;
            #pragma unroll
            for (int j = 0; j < 16; ++j) {
                float4 q = *(const float4*)&sc_y[(u << 6) + ((j << 2) ^ ((u & 15) << 2))];
                s += (q.x + q.y) + (q.z + q.w);
            }
            __builtin_nontemporal_store(s + b2v,
                &out[((size_t)(R0 + (u >> 2)) * TT + (t - 1)) * OO + O0 + (u & 3)]);
        }
        asm volatile("s_waitcnt vmcnt(0)" ::: "memory");
        __syncthreads();                  // S3
        if (tid == 0)
            __hip_atomic_store(&flags[(size_t)(t + 1) * NBLK + blk], 1,
                               __ATOMIC_RELAXED, __HIP_MEMORY_SCOPE_AGENT);
    }

    // epilogue: y_{TT-1} from h_TT
    {
        const int* fp = flags + (size_t)TT * NBLK + (bi << 6) + (tid >> 2);
        while (__hip_atomic_load((int*)fp, __ATOMIC_RELAXED,
                                 __HIP_MEMORY_SCOPE_AGENT) == 0) {}
        const ull* hsrc = (const ull*)hb[TT & 1];
        ull* vd = (ull*)v_s;
        #pragma unroll
        for (int half = 0; half < 2; ++half) {
            ull hl[8];
            #pragma unroll
            for (int m = 0; m < 8; ++m) {
                int row = (half << 3) + m;
                hl[m] = __hip_atomic_load(
                    (ull*)&hsrc[(size_t)(R0 + row) * (HH / 2) + tid],
                    __ATOMIC_RELAXED, __HIP_MEMORY_SCOPE_AGENT);
            }
            #pragma unroll
            for (int m = 0; m < 8; ++m) {
                int row = (half << 3) + m;
                vd[row * (HH / 2) + tid] = hl[m];
            }
        }
        __syncthreads();
        float py[4][4];
        #pragma unroll
        for (int r = 0; r < 4; ++r) {
            #pragma unroll
            for (int o = 0; o < 4; ++o) py[r][o] = 0.f;
            const float* vrow = v_s + (rq + (r << 2)) * HH;
            #pragma unroll
            for (int jj = 0; jj < 2; ++jj) {
                float4 vv = *(const float4*)(vrow + (jj << 8) + (g << 2));
                float vva[4] = { vv.x, vv.y, vv.z, vv.w };
                #pragma unroll
                for (int i = 0; i < 4; ++i) {
                    const float vi = vva[i];
                    #pragma unroll
                    for (int o = 0; o < 4; ++o)
                        py[r][o] = fmaf(vi, w2r[jj][i][o], py[r][o]);
                }
            }
            const int row = rq + (r << 2);
            #pragma unroll
            for (int o = 0; o < 4; ++o) {
                const int u = (row << 2) + o;
                sc_y[(u << 6) + (g ^ ((u & 15) << 2))] = py[r][o];
            }
        }
        __syncthreads();
        if (tid >= 128 && tid < 192) {
            const int u = tid - 128;
            float s = 0.f;
            #pragma unroll
            for (int j = 0; j < 16; ++j) {
                float4 q = *(const float4*)&sc_y[(u << 6) + ((j << 2) ^ ((u & 15) << 2))];
                s += (q.x + q.y) + (q.z + q.w);
            }
            out[((size_t)(R0 + (u >> 2)) * TT + (TT - 1)) * OO + O0 + (u & 3)] = s + b2v;
        }
    }
}

// ---------------- Fallback: verbatim R11 kernel (passed, 11.7ms) -------------
__global__ __launch_bounds__(256, 1) void rnn_persist_fb(
    const float* __restrict__ x, const float* __restrict__ W1,
    const float* __restrict__ b1, const float* __restrict__ W2,
    const float* __restrict__ b2, float* __restrict__ out,
    int* __restrict__ flags, float* __restrict__ hbuf)
{
    __shared__ float v_s[16 * HH];
    __shared__ float sc_h[128 * 64];
    __shared__ float sc_y[64 * 64];

    const int tid = threadIdx.x;
    const int blk = blockIdx.x;
    const int bi  = blk >> 6;
    const int cj  = blk & 63;
    const int R0  = bi << 4;
    const int C0  = cj << 3;
    const int O0  = cj << 2;

    const int g  = tid & 63;
    const int rq = tid >> 6;

    float w1r[3][4][8];
    #pragma unroll
    for (int jj = 0; jj < 3; ++jj)
        #pragma unroll
        for (int i = 0; i < 4; ++i) {
            const float* wp = W1 + (size_t)((jj << 8) + (g << 2) + i) * HH + C0;
            float4 a = *(const float4*)wp;
            float4 b = *(const float4*)(wp + 4);
            w1r[jj][i][0]=a.x; w1r[jj][i][1]=a.y; w1r[jj][i][2]=a.z; w1r[jj][i][3]=a.w;
            w1r[jj][i][4]=b.x; w1r[jj][i][5]=b.y; w1r[jj][i][6]=b.z; w1r[jj][i][7]=b.w;
        }
    float w2r[2][4][4];
    #pragma unroll
    for (int jj = 0; jj < 2; ++jj)
        #pragma unroll
        for (int i = 0; i < 4; ++i) {
            float4 a = *(const float4*)(W2 + (size_t)((jj << 8) + (g << 2) + i) * OO + O0);
            w2r[jj][i][0]=a.x; w2r[jj][i][1]=a.y; w2r[jj][i][2]=a.z; w2r[jj][i][3]=a.w;
        }
    const float b1v = (tid < 128) ? b1[C0 + (tid & 7)] : 0.f;
    const float b2v = (tid >= 128 && tid < 192) ? b2[O0 + ((tid - 128) & 3)] : 0.f;

    float* hb[2] = { hbuf, hbuf + (size_t)BB * HH };

    #pragma unroll
    for (int m = 0; m < 8; ++m)
        *(float4*)&v_s[((m << 8) + tid) << 2] = make_float4(0.f, 0.f, 0.f, 0.f);

    fx4 xreg[4];
    #pragma unroll
    for (int r = 0; r < 4; ++r)
        xreg[r] = __builtin_nontemporal_load(
            (const fx4*)&x[((size_t)(R0 + rq + (r << 2)) * TT + 0) * II + (g << 2)]);
    __syncthreads();

    for (int t = 0; t < TT; ++t) {
        float pa[4][8];
        float py[4][4];
        #pragma unroll
        for (int r = 0; r < 4; ++r) {
            #pragma unroll
            for (int c = 0; c < 8; ++c) pa[r][c] = 0.f;
            #pragma unroll
            for (int o = 0; o < 4; ++o) py[r][o] = 0.f;
        }
        #pragma unroll
        for (int r = 0; r < 4; ++r) {
            fx4 vv = xreg[r];
            #pragma unroll
            for (int i = 0; i < 4; ++i) {
                const float vi = vv[i];
                #pragma unroll
                for (int c = 0; c < 8; ++c)
                    pa[r][c] = fmaf(vi, w1r[2][i][c], pa[r][c]);
            }
        }
        if (t > 0) {
            const int* fp = flags + (size_t)t * NBLK + (bi << 6) + (tid >> 2);
            while (__hip_atomic_load((int*)fp, __ATOMIC_RELAXED,
                                     __HIP_MEMORY_SCOPE_AGENT) == 0) {}
            const ull* hsrc = (const ull*)hb[t & 1];
            ull* vd = (ull*)v_s;
            #pragma unroll
            for (int half = 0; half < 2; ++half) {
                ull hl[8];
                #pragma unroll
                for (int m = 0; m < 8; ++m) {
                    int row = (half << 3) + m;
                    hl[m] = __hip_atomic_load(
                        (ull*)&hsrc[(size_t)(R0 + row) * (HH / 2) + tid],
                        __ATOMIC_RELAXED, __HIP_MEMORY_SCOPE_AGENT);
                }
                #pragma unroll
                for (int m = 0; m < 8; ++m) {
                    int row = (half << 3) + m;
                    vd[row * (HH / 2) + tid] = hl[m];
                }
            }
        }
        __syncthreads();

        #pragma unroll
        for (int r = 0; r < 4; ++r) {
            const float* vrow = v_s + (rq + (r << 2)) * HH;
            #pragma unroll
            for (int jj = 0; jj < 2; ++jj) {
                float4 vv = *(const float4*)(vrow + (jj << 8) + (g << 2));
                float vva[4] = { vv.x, vv.y, vv.z, vv.w };
                #pragma unroll
                for (int i = 0; i < 4; ++i) {
                    const float vi = vva[i];
                    #pragma unroll
                    for (int c = 0; c < 8; ++c)
                        pa[r][c] = fmaf(vi, w1r[jj][i][c], pa[r][c]);
                    #pragma unroll
                    for (int o = 0; o < 4; ++o)
                        py[r][o] = fmaf(vi, w2r[jj][i][o], py[r][o]);
                }
            }
        }
        #pragma unroll
        for (int r = 0; r < 4; ++r) {
            const int row = rq + (r << 2);
            #pragma unroll
            for (int c = 0; c < 8; ++c) {
                const int u = (row << 3) + c;
                sc_h[(u << 6) + (g ^ ((u & 15) << 2))] = pa[r][c];
            }
            #pragma unroll
            for (int o = 0; o < 4; ++o) {
                const int u = (row << 2) + o;
                sc_y[(u << 6) + (g ^ ((u & 15) << 2))] = py[r][o];
            }
        }
        __syncthreads();

        if (tid < 128) {
            float s = 0.f;
            #pragma unroll
            for (int j = 0; j < 16; ++j) {
                float4 q = *(const float4*)&sc_h[(tid << 6) + ((j << 2) ^ ((tid & 15) << 2))];
                s += (q.x + q.y) + (q.z + q.w);
            }
            float hv = tanhf(s + b1v);
            __hip_atomic_store(&hb[(t + 1) & 1][(size_t)(R0 + (tid >> 3)) * HH + C0 + (tid & 7)],
                               hv, __ATOMIC_RELAXED, __HIP_MEMORY_SCOPE_AGENT);
            if (t == TT - 1)
                out[OUT_OFF + (size_t)(R0 + (tid >> 3)) * HH + C0 + (tid & 7)] = hv;
        } else if (tid < 192 && t > 0) {
            const int u = tid - 128;
            float s = 0.f;
            #pragma unroll
            for (int j = 0; j < 16; ++j) {
                float4 q = *(const float4*)&sc_y[(u << 6) + ((j << 2) ^ ((u & 15) << 2))];
                s += (q.x + q.y) + (q.z + q.w);
            }
            __builtin_nontemporal_store(s + b2v,
                &out[((size_t)(R0 + (u >> 2)) * TT + (t - 1)) * OO + O0 + (u & 3)]);
        }
        asm volatile("s_waitcnt vmcnt(0)" ::: "memory");
        __syncthreads();
        if (tid == 0)
            __hip_atomic_store(&flags[(size_t)(t + 1) * NBLK + blk], 1,
                               __ATOMIC_RELAXED, __HIP_MEMORY_SCOPE_AGENT);
        if (t + 1 < TT) {
            #pragma unroll
            for (int r = 0; r < 4; ++r)
                xreg[r] = __builtin_nontemporal_load(
                    (const fx4*)&x[((size_t)(R0 + rq + (r << 2)) * TT + (t + 1)) * II + (g << 2)]);
        }
    }

    {
        const int* fp = flags + (size_t)TT * NBLK + (bi << 6) + (tid >> 2);
        while (__hip_atomic_load((int*)fp, __ATOMIC_RELAXED,
                                 __HIP_MEMORY_SCOPE_AGENT) == 0) {}
        const ull* hsrc = (const ull*)hb[TT & 1];
        ull* vd = (ull*)v_s;
        #pragma unroll
        for (int half = 0; half < 2; ++half) {
            ull hl[8];
            #pragma unroll
            for (int m = 0; m < 8; ++m) {
                int row = (half << 3) + m;
                hl[m] = __hip_atomic_load(
                    (ull*)&hsrc[(size_t)(R0 + row) * (HH / 2) + tid],
                    __ATOMIC_RELAXED, __HIP_MEMORY_SCOPE_AGENT);
            }
            #pragma unroll
            for (int m = 0; m < 8; ++m) {
                int row = (half << 3) + m;
                vd[row * (HH / 2) + tid] = hl[m];
            }
        }
        __syncthreads();
        float py[4][4];
        #pragma unroll
        for (int r = 0; r < 4; ++r) {
            #pragma unroll
            for (int o = 0; o < 4; ++o) py[r][o] = 0.f;
            const float* vrow = v_s + (rq + (r << 2)) * HH;
            #pragma unroll
            for (int jj = 0; jj < 2; ++jj) {
                float4 vv = *(const float4*)(vrow + (jj << 8) + (g << 2));
                float vva[4] = { vv.x, vv.y, vv.z, vv.w };
                #pragma unroll
                for (int i = 0; i < 4; ++i) {
                    const float vi = vva[i];
                    #pragma unroll
                    for (int o = 0; o < 4; ++o)
                        py[r][o] = fmaf(vi, w2r[jj][i][o], py[r][o]);
                }
            }
            const int row = rq + (r << 2);
            #pragma unroll
            for (int o = 0; o < 4; ++o) {
                const int u = (row << 2) + o;
                sc_y[(u << 6) + (g ^ ((u & 15) << 2))] = py[r][o];
            }
        }
        __syncthreads();
        if (tid >= 128 && tid < 192) {
            const int u = tid - 128;
            float s = 0.f;
            #pragma unroll
            for (int j = 0; j < 16; ++j) {
                float4 q = *(const float4*)&sc_y[(u << 6) + ((j << 2) ^ ((u & 15) << 2))];
                s += (q.x + q.y) + (q.z + q.w);
            }
            out[((size_t)(R0 + (u >> 2)) * TT + (TT - 1)) * OO + O0 + (u & 3)] = s + b2v;
        }
    }
}

extern "C" void kernel_launch(void* const* d_in, const int* in_sizes, int n_in,
                              void* d_out, int out_size, void* d_ws, size_t ws_size,
                              hipStream_t stream) {
    const float* x  = (const float*)d_in[0];
    const float* W1 = (const float*)d_in[1];
    const float* b1 = (const float*)d_in[2];
    const float* W2 = (const float*)d_in[3];
    const float* b2 = (const float*)d_in[4];
    float* out = (float*)d_out;

    float* hbuf  = (float*)d_ws;                        // 256KB ping-pong
    int*   flags = (int*)((char*)d_ws + 512 * 1024);    // ~2.1MB

    rnn_init<<<dim3((FLAGS_INTS + 255) / 256), dim3(256), 0, stream>>>(flags);

    if (ws_size >= XW_OFF + XW_BYTES) {
        float* xwbuf = (float*)((char*)d_ws + XW_OFF);  // 268MB
        xw_gemm<<<dim3(16384), dim3(256), 0, stream>>>(x, W1, xwbuf);
        rnn_persist_xw<<<dim3(NBLK), dim3(256), 0, stream>>>(xwbuf, W1, b1, W2, b2,
                                                             out, flags, hbuf);
    } else {
        rnn_persist_fb<<<dim3(NBLK), dim3(256), 0, stream>>>(x, W1, b1, W2, b2,
                                                             out, flags, hbuf);
    }
}